// Round 4
// baseline (723.564 us; speedup 1.0000x reference)
//
#include <hip/hip_runtime.h>
#include <hip/hip_bf16.h>

// ---------------------------------------------------------------------------
// concat(x1,x2) -> LSTM(551->128, T=5) -> MLP 640->531->256->64->2 -> softmax
// R4: two dispatches.
//  stage : (blocks 0..511)  x fp32 -> bf16 packed A-tiles `xp` via LDS
//          (coalesced reads, 16B/lane tile writes, zero-padded k 551..575)
//          (blocks 512..959) weight repack (prep) hidden behind the stream.
//  fused : R3 structure, but x@W_ih reads packed tiles (16B/lane, 1-deep
//          prefetch, L1-shared across 8 waves) -- no scattered fp32, no cvts.
// Packed A/B-tile: 16(m|n) x 32(k) = 512 elems; pos = lane*8+j,
//   lane = ((k>>3)&3)*16 + (m&15), j = k&7.
// ---------------------------------------------------------------------------

typedef short  short8  __attribute__((ext_vector_type(8)));
typedef short  short4v __attribute__((ext_vector_type(4)));
typedef float  f32x4   __attribute__((ext_vector_type(4)));

#define MFMA(a, b, c) __builtin_amdgcn_mfma_f32_16x16x32_bf16((a), (b), (c), 0, 0, 0)

__device__ __forceinline__ short f2bs(float f) {
    __hip_bfloat16 h = __float2bfloat16(f);   // RNE
    union { __hip_bfloat16 h; short s; } u; u.h = h; return u.s;
}
__device__ __forceinline__ float b2f(short s) {
    union { unsigned u; float f; } v; v.u = ((unsigned)(unsigned short)s) << 16; return v.f;
}
__device__ __forceinline__ float sigf(float x)  { return 1.f / (1.f + __expf(-x)); }
__device__ __forceinline__ float mytanh(float x){ return 2.f / (1.f + __expf(-2.f * x)) - 1.f; }

// ---------------- constants ----------------
#define TT     5
#define F1     300
#define F2     251
#define INF    551
#define G4     512
#define HH     128
#define FLAT   640          // T*H (20 k-tiles)
#define L1N    531
#define L1KP   544          // 17 k-tiles
#define L2N    256

#define NXPACK 512          // xpack blocks in stage kernel
#define NPREP  448          // prep blocks in stage kernel

// ws offsets (bytes)
#define O_WIH  0u
#define O_WHH  589824u
#define O_W1   720896u
#define O_W2   1458176u
#define O_W3   1736704u
#define O_BG   1769472u
#define O_B1   1771520u
#define O_XP   1773824u     // xp: 1024 tm x 5 t x 18 kt x 1024 B = 94,371,840
#define WS_NEED 96145664u

// fused-kernel LDS plan (shorts)
#define SM_TOTAL 39424
#define AFL_STR  648
#define A1_OFF   20736
#define A1_STR   584
#define A2_OFF   0
#define A2_STR   264
#define A3_OFF   8448
#define A3_STR   72

// ---------------------------------------------------------------------------
// stage kernel: xpack (blocks < NXPACK) + weight prep (blocks >= NXPACK)
// ---------------------------------------------------------------------------
__device__ __forceinline__ void pack_b(const float* __restrict__ W, short* __restrict__ dst,
                                       int i, int tpn, int Nsrc, int Ksrc, int ldw)
{
    int tile = i >> 9, rem = i & 511, lane = rem >> 3, jj = rem & 7;
    int tn = tile / tpn, tk = tile - tn * tpn;
    int n = tn * 16 + (lane & 15);
    int k = tk * 32 + (lane >> 4) * 8 + jj;
    float v = (n < Nsrc && k < Ksrc) ? W[n * ldw + k] : 0.f;
    dst[i] = f2bs(v);
}

__global__ __launch_bounds__(256, 4) void stage_kernel(
    const float* __restrict__ x1, const float* __restrict__ x2,
    const float* __restrict__ W_ih, const float* __restrict__ W_hh,
    const float* __restrict__ b_ih, const float* __restrict__ b_hh,
    const float* __restrict__ W1,   const float* __restrict__ b1,
    const float* __restrict__ W2,   const float* __restrict__ W3,
    short* __restrict__ Wihp, short* __restrict__ Whhp, float* __restrict__ biasg,
    short* __restrict__ W1p,  float* __restrict__ b1p,  short* __restrict__ W2p,
    short* __restrict__ W3p,  short* __restrict__ xp)
{
    __shared__ __align__(16) short sX[32][584];
    const int tid = threadIdx.x;

    if (blockIdx.x < NXPACK) {
        // ---------------- xpack: 32 samples/block ----------------
        const int b0 = blockIdx.x * 32;
        // zero k-pad cols [544,576) once (551..575 stay zero through all t)
        for (int idx = tid; idx < 32 * 32; idx += 256) {
            int r = idx >> 5, c = 544 + (idx & 31);
            sX[r][c] = 0;
        }
        __syncthreads();

        const int r  = tid >> 3;       // 0..31
        const int c8 = tid & 7;        // 0..7
        const int lane = tid & 63;
        const int wv   = tid >> 6;     // 0..3

        for (int t = 0; t < TT; ++t) {
            // x1 slice: 75 float4 per row, 16B-aligned
            {
                const float* xr = x1 + ((b0 + r) * TT + t) * F1;
#pragma unroll 4
                for (int c4 = c8; c4 < 75; c4 += 8) {
                    float4 v = *(const float4*)(xr + c4 * 4);
                    short4v s;
                    s[0] = f2bs(v.x); s[1] = f2bs(v.y); s[2] = f2bs(v.z); s[3] = f2bs(v.w);
                    *(short4v*)&sX[r][c4 * 4] = s;
                }
            }
            // x2 slice: 251 scalars per row (rows not 16B-aligned)
            {
                const float* xr = x2 + ((b0 + r) * TT + t) * F2;
#pragma unroll 8
                for (int c = c8; c < F2; c += 8)
                    sX[r][F1 + c] = f2bs(xr[c]);
            }
            __syncthreads();
            // emit 36 packed tiles (2 tm x 18 kt), 9 per wave
#pragma unroll
            for (int i = 0; i < 9; ++i) {
                int tau = wv + i * 4;
                int tm  = (tau >= 18) ? 1 : 0;
                int kt  = tau - tm * 18;
                short8 v = *(const short8*)&sX[tm * 16 + (lane & 15)][kt * 32 + (lane >> 4) * 8];
                *(short8*)&xp[(((blockIdx.x * 2 + tm) * TT + t) * 18 + kt) * 512 + lane * 8] = v;
            }
            __syncthreads();
        }
    } else {
        // ---------------- prep: weight repack ----------------
        const int N0 = G4 * 576;           // Wihp (18 k-tiles)
        const int N1 = N0 + G4 * HH;       // Whhp (4 k-tiles)
        const int N2 = N1 + 576 * FLAT;    // W1p  (20 k-tiles)
        const int N3 = N2 + L2N * L1KP;    // W2p  (17 k-tiles)
        const int N4 = N3 + 64 * L2N;      // W3p  (8 k-tiles)
        const int N5 = N4 + G4;            // biasg
        const int N6 = N5 + 576;           // b1p
        const int stride = NPREP * 256;
        for (int i = (blockIdx.x - NXPACK) * 256 + tid; i < N6; i += stride) {
            if (i < N0)      pack_b(W_ih, Wihp, i,       18, G4,  INF, INF);
            else if (i < N1) pack_b(W_hh, Whhp, i - N0,   4, G4,  HH,  HH);
            else if (i < N2) pack_b(W1,   W1p,  i - N1,  20, L1N, FLAT, FLAT);
            else if (i < N3) pack_b(W2,   W2p,  i - N2,  17, L2N, L1N, L1N);
            else if (i < N4) pack_b(W3,   W3p,  i - N3,   8, 64,  L2N, L2N);
            else if (i < N5) { int j = i - N4; biasg[j] = b_ih[j] + b_hh[j]; }
            else             { int j = i - N5; b1p[j] = (j < L1N) ? b1[j] : 0.f; }
        }
    }
}

// ---------------------------------------------------------------------------
// fused kernel: 512 blocks x 512 thr, 32 samples/block.
// x@W_ih from packed tiles; gates in AGPRs; W_hh in regs; h via LDS; MLP.
// ---------------------------------------------------------------------------
__global__ __launch_bounds__(512, 4) void fused_kernel(
    const short* __restrict__ xp,
    const short* __restrict__ Wihp, const short* __restrict__ Whhp,
    const float* __restrict__ biasg,
    const short* __restrict__ W1p, const float* __restrict__ b1p,
    const short* __restrict__ W2p, const float* __restrict__ b2,
    const short* __restrict__ W3p, const float* __restrict__ b3,
    const float* __restrict__ W4,  const float* __restrict__ b4,
    float* __restrict__ out)
{
    __shared__ __align__(16) short sA[SM_TOTAL];
    const int tid  = threadIdx.x;
    const int w    = tid >> 6;
    const int lane = tid & 63;
    const int quad = lane >> 4;
    const int c16  = lane & 15;
    const int b0   = blockIdx.x * 32;
    const int j    = w * 16 + c16;          // gate-local column 0..127

    float bg[4];
#pragma unroll
    for (int g = 0; g < 4; ++g) bg[g] = biasg[g * HH + j];

    // W_hh B-frags resident in registers (reused all t)
    short8 whh[4][4];
#pragma unroll
    for (int g = 0; g < 4; ++g)
#pragma unroll
        for (int ks = 0; ks < 4; ++ks)
            whh[g][ks] = *(const short8*)&Whhp[((((g * 8 + w) * 4) + ks) << 9) + lane * 8];

    float cst[2][4];
#pragma unroll
    for (int mt = 0; mt < 2; ++mt)
#pragma unroll
        for (int r = 0; r < 4; ++r) cst[mt][r] = 0.f;

    // ---------------- recurrence over t ----------------
    for (int t = 0; t < TT; ++t) {
        f32x4 acc[2][4];
#pragma unroll
        for (int mt = 0; mt < 2; ++mt)
#pragma unroll
            for (int g = 0; g < 4; ++g)
                acc[mt][g] = (f32x4){0.f, 0.f, 0.f, 0.f};

        // ---- x @ W_ih^T from packed tiles (18 k-tiles, 1-deep prefetch) ----
        {
            const short* xpt0 = xp + ((blockIdx.x * 2 + 0) * TT + t) * 18 * 512 + lane * 8;
            const short* xpt1 = xp + ((blockIdx.x * 2 + 1) * TT + t) * 18 * 512 + lane * 8;
            short8 a0 = *(const short8*)(xpt0);
            short8 a1 = *(const short8*)(xpt1);
#pragma unroll
            for (int tk = 0; tk < 18; ++tk) {
                short8 na0, na1;
                if (tk < 17) {
                    na0 = *(const short8*)(xpt0 + (tk + 1) * 512);
                    na1 = *(const short8*)(xpt1 + (tk + 1) * 512);
                }
#pragma unroll
                for (int g = 0; g < 4; ++g) {
                    short8 bfr = *(const short8*)&Wihp[(((g * 8 + w) * 18 + tk) << 9) + lane * 8];
                    acc[0][g] = MFMA(a0, bfr, acc[0][g]);
                    acc[1][g] = MFMA(a1, bfr, acc[1][g]);
                }
                a0 = na0; a1 = na1;
            }
        }

        // ---- + h_{t-1} @ W_hh^T from LDS ----
        if (t > 0) {
#pragma unroll
            for (int ks = 0; ks < 4; ++ks) {
                short8 ha[2];
#pragma unroll
                for (int mt = 0; mt < 2; ++mt)
                    ha[mt] = *(const short8*)
                        &sA[(mt * 16 + c16) * AFL_STR + (t - 1) * HH + ks * 32 + quad * 8];
#pragma unroll
                for (int g = 0; g < 4; ++g) {
                    acc[0][g] = MFMA(ha[0], whh[g][ks], acc[0][g]);
                    acc[1][g] = MFMA(ha[1], whh[g][ks], acc[1][g]);
                }
            }
        }

        // ---- gates -> c,h ; h into aflat ----
#pragma unroll
        for (int mt = 0; mt < 2; ++mt) {
#pragma unroll
            for (int r = 0; r < 4; ++r) {
                int m = mt * 16 + quad * 4 + r;
                float gi = acc[mt][0][r] + bg[0];
                float gf = acc[mt][1][r] + bg[1];
                float gg = acc[mt][2][r] + bg[2];
                float go = acc[mt][3][r] + bg[3];
                float cn = sigf(gf) * cst[mt][r] + sigf(gi) * mytanh(gg);
                cst[mt][r] = cn;
                sA[m * AFL_STR + t * HH + j] = f2bs(sigf(go) * mytanh(cn));
            }
        }
        __syncthreads();
    }

    // ---------------- MLP ----------------
    // L1: K=640, N=576; 36 n-tiles, wave w gets tn = w + 8i
    {
        const int ntc = (w < 4) ? 5 : 4;
        f32x4 acc1[2][5];
#pragma unroll
        for (int mt = 0; mt < 2; ++mt)
#pragma unroll
            for (int i = 0; i < 5; ++i)
                acc1[mt][i] = (f32x4){0.f, 0.f, 0.f, 0.f};
        for (int ks = 0; ks < 20; ++ks) {
            short8 a[2];
#pragma unroll
            for (int mt = 0; mt < 2; ++mt)
                a[mt] = *(const short8*)&sA[(mt * 16 + c16) * AFL_STR + ks * 32 + quad * 8];
#pragma unroll
            for (int i = 0; i < 5; ++i) {
                if (i < ntc) {
                    int tn = w + 8 * i;
                    short8 b = *(const short8*)&W1p[((tn * 20 + ks) << 9) + lane * 8];
                    acc1[0][i] = MFMA(a[0], b, acc1[0][i]);
                    acc1[1][i] = MFMA(a[1], b, acc1[1][i]);
                }
            }
        }
        __syncthreads();
#pragma unroll
        for (int i = 0; i < 5; ++i) {
            if (i < ntc) {
                int tn = w + 8 * i;
                int n  = tn * 16 + c16;
                float bv = b1p[n];
#pragma unroll
                for (int mt = 0; mt < 2; ++mt)
#pragma unroll
                    for (int r = 0; r < 4; ++r) {
                        int m = mt * 16 + quad * 4 + r;
                        float v = acc1[mt][i][r] + bv;
                        sA[A1_OFF + m * A1_STR + n] = f2bs(v > 0.f ? v : 0.f);
                    }
            }
        }
    }
    __syncthreads();

    // L2: K=544, N=256; wave w gets tn = 2w, 2w+1 (a2 overwrites aflat)
    {
        f32x4 acc2[2][2];
#pragma unroll
        for (int mt = 0; mt < 2; ++mt)
#pragma unroll
            for (int i = 0; i < 2; ++i)
                acc2[mt][i] = (f32x4){0.f, 0.f, 0.f, 0.f};
        for (int ks = 0; ks < 17; ++ks) {
            short8 a[2];
#pragma unroll
            for (int mt = 0; mt < 2; ++mt)
                a[mt] = *(const short8*)&sA[A1_OFF + (mt * 16 + c16) * A1_STR + ks * 32 + quad * 8];
#pragma unroll
            for (int i = 0; i < 2; ++i) {
                int tn = w * 2 + i;
                short8 b = *(const short8*)&W2p[((tn * 17 + ks) << 9) + lane * 8];
                acc2[0][i] = MFMA(a[0], b, acc2[0][i]);
                acc2[1][i] = MFMA(a[1], b, acc2[1][i]);
            }
        }
#pragma unroll
        for (int i = 0; i < 2; ++i) {
            int n = (w * 2 + i) * 16 + c16;
            float bv = b2[n];
#pragma unroll
            for (int mt = 0; mt < 2; ++mt)
#pragma unroll
                for (int r = 0; r < 4; ++r) {
                    int m = mt * 16 + quad * 4 + r;
                    float v = acc2[mt][i][r] + bv;
                    sA[A2_OFF + m * A2_STR + n] = f2bs(v > 0.f ? v : 0.f);
                }
        }
    }
    __syncthreads();

    // L3: K=256, N=64; waves 0..3
    if (w < 4) {
        f32x4 acc3[2];
        acc3[0] = (f32x4){0.f, 0.f, 0.f, 0.f};
        acc3[1] = (f32x4){0.f, 0.f, 0.f, 0.f};
#pragma unroll
        for (int ks = 0; ks < 8; ++ks) {
            short8 a[2];
#pragma unroll
            for (int mt = 0; mt < 2; ++mt)
                a[mt] = *(const short8*)&sA[A2_OFF + (mt * 16 + c16) * A2_STR + ks * 32 + quad * 8];
            short8 b = *(const short8*)&W3p[((w * 8 + ks) << 9) + lane * 8];
            acc3[0] = MFMA(a[0], b, acc3[0]);
            acc3[1] = MFMA(a[1], b, acc3[1]);
        }
        int n = w * 16 + c16;
        float bv = b3[n];
#pragma unroll
        for (int mt = 0; mt < 2; ++mt)
#pragma unroll
            for (int r = 0; r < 4; ++r) {
                int m = mt * 16 + quad * 4 + r;
                float v = acc3[mt][r] + bv;
                sA[A3_OFF + m * A3_STR + n] = f2bs(v > 0.f ? v : 0.f);
            }
    }
    __syncthreads();

    // L4 + softmax: 64 threads = 32 samples x 2 classes
    if (tid < 64) {
        int m   = tid >> 1;
        int cls = tid & 1;
        float s = b4[cls];
#pragma unroll 8
        for (int k = 0; k < 64; ++k)
            s += b2f(sA[A3_OFF + m * A3_STR + k]) * W4[cls * 64 + k];
        float other = __shfl_xor(s, 1);
        float p = 1.f / (1.f + __expf(other - s));
        out[(b0 + m) * 2 + cls] = p;
    }
}

// ---------------------------------------------------------------------------
extern "C" void kernel_launch(void* const* d_in, const int* in_sizes, int n_in,
                              void* d_out, int out_size, void* d_ws, size_t ws_size,
                              hipStream_t stream)
{
    (void)in_sizes; (void)n_in; (void)out_size;
    if (ws_size < (size_t)WS_NEED) return;

    const float* x1   = (const float*)d_in[0];
    const float* x2   = (const float*)d_in[1];
    const float* W_ih = (const float*)d_in[2];
    const float* W_hh = (const float*)d_in[3];
    const float* b_ih = (const float*)d_in[4];
    const float* b_hh = (const float*)d_in[5];
    const float* W1   = (const float*)d_in[6];
    const float* b1   = (const float*)d_in[7];
    const float* W2   = (const float*)d_in[8];
    const float* b2   = (const float*)d_in[9];
    const float* W3   = (const float*)d_in[10];
    const float* b3   = (const float*)d_in[11];
    const float* W4   = (const float*)d_in[12];
    const float* b4   = (const float*)d_in[13];

    char* ws = (char*)d_ws;
    short* Wihp  = (short*)(ws + O_WIH);
    short* Whhp  = (short*)(ws + O_WHH);
    short* W1p   = (short*)(ws + O_W1);
    short* W2p   = (short*)(ws + O_W2);
    short* W3p   = (short*)(ws + O_W3);
    float* biasg = (float*)(ws + O_BG);
    float* b1p   = (float*)(ws + O_B1);
    short* xp    = (short*)(ws + O_XP);

    stage_kernel<<<NXPACK + NPREP, 256, 0, stream>>>(
        x1, x2, W_ih, W_hh, b_ih, b_hh, W1, b1, W2, W3,
        Wihp, Whhp, biasg, W1p, b1p, W2p, W3p, xp);
    fused_kernel<<<512, 512, 0, stream>>>(
        xp, Wihp, Whhp, biasg, W1p, b1p, W2p, b2, W3p, b3, W4, b4,
        (float*)d_out);
}

// Round 5
// 381.848 us; speedup vs baseline: 1.8949x; 1.8949x over previous
//
#include <hip/hip_runtime.h>
#include <hip/hip_bf16.h>

// ---------------------------------------------------------------------------
// concat(x1,x2) -> LSTM(551->128, T=5) -> MLP 640->531->256->64->2 -> softmax
// R5: 3 dispatches.
//  stage : xpack (x fp32 -> bf16 packed A-tiles, 94 MB) + weight prep.
//  k1    : barrier-free bf16 GEMM  xg = xp @ W_ih^T + bias.  BM=128, N=512
//          in-block (8 n-waves => A read once/block, L1-shared), A+B packed
//          16B/lane loads w/ 1-deep prefetch, acc in AGPRs.  Epilogue stores
//          xg C-tiles IN-PLACE over the block's own xp region (no extra ws).
//  k23   : recurrence + MLP fused, 64 samples/block, 256 blocks (1/CU).
//          W_hh in regs, gates in AGPRs, h + activations in LDS.
// Packed A/B-tile: 16(m|n) x 32(k) = 512 elems; pos = lane*8+j,
//   lane = ((k>>3)&3)*16 + (m&15), j = k&7.   (1 KB per tile)
// Packed C-tile: 16x16; pos = lane*4+r, lane = ((m>>2)&3)*16+(n&15), r=m&3.
// m-tile index g = sample_tile*5 + t  (5120 m-tiles total).
// ---------------------------------------------------------------------------

typedef short  short8  __attribute__((ext_vector_type(8)));
typedef short  short4v __attribute__((ext_vector_type(4)));
typedef float  f32x4   __attribute__((ext_vector_type(4)));

#define MFMA(a, b, c) __builtin_amdgcn_mfma_f32_16x16x32_bf16((a), (b), (c), 0, 0, 0)

__device__ __forceinline__ short f2bs(float f) {
    __hip_bfloat16 h = __float2bfloat16(f);   // RNE
    union { __hip_bfloat16 h; short s; } u; u.h = h; return u.s;
}
__device__ __forceinline__ float b2f(short s) {
    union { unsigned u; float f; } v; v.u = ((unsigned)(unsigned short)s) << 16; return v.f;
}
__device__ __forceinline__ float sigf(float x)  { return 1.f / (1.f + __expf(-x)); }
__device__ __forceinline__ float mytanh(float x){ return 2.f / (1.f + __expf(-2.f * x)) - 1.f; }

// ---------------- constants ----------------
#define TT     5
#define F1     300
#define F2     251
#define INF    551
#define G4     512
#define HH     128
#define FLAT   640          // T*H (20 k-tiles)
#define L1N    531
#define L1KP   544          // 17 k-tiles
#define L2N    256

#define NXPACK 512
#define NPREP  448

// ws offsets (bytes) — total is the R4-proven 96,145,664
#define O_WIH  0u
#define O_WHH  589824u
#define O_W1   720896u
#define O_W2   1458176u
#define O_W3   1736704u
#define O_BG   1769472u
#define O_B1   1771520u
#define O_XP   1773824u     // xp: 5120 m-tiles x 18 kt x 1 KB = 94,371,840
#define WS_NEED 96145664u

// k23 LDS plan (shorts): aflat [64][648] at 0; a1 [64][584] at 41472.
// After aflat dies: a2 [64][264] at 0; a3 [64][72] at 16896.
#define AFL_STR  648
#define A1_OFF   41472
#define A1_STR   584
#define A2_OFF   0
#define A2_STR   264
#define A3_OFF   16896
#define A3_STR   72
#define SM_SHORTS 78848     // 157,696 B

// ---------------------------------------------------------------------------
// stage kernel: xpack (blocks < NXPACK) + weight prep (blocks >= NXPACK)
// ---------------------------------------------------------------------------
__device__ __forceinline__ void pack_b(const float* __restrict__ W, short* __restrict__ dst,
                                       int i, int tpn, int Nsrc, int Ksrc, int ldw)
{
    int tile = i >> 9, rem = i & 511, lane = rem >> 3, jj = rem & 7;
    int tn = tile / tpn, tk = tile - tn * tpn;
    int n = tn * 16 + (lane & 15);
    int k = tk * 32 + (lane >> 4) * 8 + jj;
    float v = (n < Nsrc && k < Ksrc) ? W[n * ldw + k] : 0.f;
    dst[i] = f2bs(v);
}

__global__ __launch_bounds__(256, 4) void stage_kernel(
    const float* __restrict__ x1, const float* __restrict__ x2,
    const float* __restrict__ W_ih, const float* __restrict__ W_hh,
    const float* __restrict__ b_ih, const float* __restrict__ b_hh,
    const float* __restrict__ W1,   const float* __restrict__ b1,
    const float* __restrict__ W2,   const float* __restrict__ W3,
    short* __restrict__ Wihp, short* __restrict__ Whhp, float* __restrict__ biasg,
    short* __restrict__ W1p,  float* __restrict__ b1p,  short* __restrict__ W2p,
    short* __restrict__ W3p,  short* __restrict__ xp)
{
    __shared__ __align__(16) short sX[32][584];
    const int tid = threadIdx.x;

    if (blockIdx.x < NXPACK) {
        const int b0 = blockIdx.x * 32;
        for (int idx = tid; idx < 32 * 32; idx += 256) {
            int r = idx >> 5, c = 544 + (idx & 31);
            sX[r][c] = 0;
        }
        __syncthreads();

        const int r  = tid >> 3;
        const int c8 = tid & 7;
        const int lane = tid & 63;
        const int wv   = tid >> 6;

        for (int t = 0; t < TT; ++t) {
            {
                const float* xr = x1 + ((b0 + r) * TT + t) * F1;
#pragma unroll 4
                for (int c4 = c8; c4 < 75; c4 += 8) {
                    float4 v = *(const float4*)(xr + c4 * 4);
                    short4v s;
                    s[0] = f2bs(v.x); s[1] = f2bs(v.y); s[2] = f2bs(v.z); s[3] = f2bs(v.w);
                    *(short4v*)&sX[r][c4 * 4] = s;
                }
            }
            {
                const float* xr = x2 + ((b0 + r) * TT + t) * F2;
#pragma unroll 8
                for (int c = c8; c < F2; c += 8)
                    sX[r][F1 + c] = f2bs(xr[c]);
            }
            __syncthreads();
#pragma unroll
            for (int i = 0; i < 9; ++i) {
                int tau = wv + i * 4;
                int tm  = (tau >= 18) ? 1 : 0;
                int kt  = tau - tm * 18;
                short8 v = *(const short8*)&sX[tm * 16 + (lane & 15)][kt * 32 + (lane >> 4) * 8];
                // m-tile g = (blockIdx.x*2+tm)*5 + t
                *(short8*)&xp[(((blockIdx.x * 2 + tm) * TT + t) * 18 + kt) * 512 + lane * 8] = v;
            }
            __syncthreads();
        }
    } else {
        const int N0 = G4 * 576;
        const int N1 = N0 + G4 * HH;
        const int N2 = N1 + 576 * FLAT;
        const int N3 = N2 + L2N * L1KP;
        const int N4 = N3 + 64 * L2N;
        const int N5 = N4 + G4;
        const int N6 = N5 + 576;
        const int stride = NPREP * 256;
        for (int i = (blockIdx.x - NXPACK) * 256 + tid; i < N6; i += stride) {
            if (i < N0)      pack_b(W_ih, Wihp, i,       18, G4,  INF, INF);
            else if (i < N1) pack_b(W_hh, Whhp, i - N0,   4, G4,  HH,  HH);
            else if (i < N2) pack_b(W1,   W1p,  i - N1,  20, L1N, FLAT, FLAT);
            else if (i < N3) pack_b(W2,   W2p,  i - N2,  17, L2N, L1N, L1N);
            else if (i < N4) pack_b(W3,   W3p,  i - N3,   8, 64,  L2N, L2N);
            else if (i < N5) { int j = i - N4; biasg[j] = b_ih[j] + b_hh[j]; }
            else             { int j = i - N5; b1p[j] = (j < L1N) ? b1[j] : 0.f; }
        }
    }
}

// ---------------------------------------------------------------------------
// k1_xgemm: 640 blocks x 512 thr. BM=128 (8 m-tiles), N=512 (wave w owns
// n-tiles 4w..4w+3). Barrier-free k-loop, 1-deep prefetch, in-place epilogue.
// ---------------------------------------------------------------------------
__global__ __launch_bounds__(512, 2) void k1_xgemm(
    short* xp,                                    // read A-tiles, write xg in-place
    const short* __restrict__ Wihp, const float* __restrict__ biasg)
{
    const int tid  = threadIdx.x;
    const int w    = tid >> 6;
    const int lane = tid & 63;
    const int c16  = lane & 15;
    const int g0   = blockIdx.x * 8;              // first m-tile

    f32x4 acc[8][4];
#pragma unroll
    for (int mt = 0; mt < 8; ++mt)
#pragma unroll
        for (int nt = 0; nt < 4; ++nt)
            acc[mt][nt] = (f32x4){0.f, 0.f, 0.f, 0.f};

    const short* abase = xp + g0 * 9216 + lane * 8;          // + (mt*18+tk)*512
    const short* bbase = Wihp + (w * 4) * 9216 + lane * 8;   // + (nt*18+tk)*512

    short8 a[8], b[4];
#pragma unroll
    for (int mt = 0; mt < 8; ++mt) a[mt] = *(const short8*)(abase + mt * 9216);
#pragma unroll
    for (int nt = 0; nt < 4; ++nt) b[nt] = *(const short8*)(bbase + nt * 9216);

    for (int tk = 0; tk < 18; ++tk) {
        short8 an[8], bn[4];
        if (tk < 17) {
#pragma unroll
            for (int mt = 0; mt < 8; ++mt)
                an[mt] = *(const short8*)(abase + mt * 9216 + (tk + 1) * 512);
#pragma unroll
            for (int nt = 0; nt < 4; ++nt)
                bn[nt] = *(const short8*)(bbase + nt * 9216 + (tk + 1) * 512);
        }
#pragma unroll
        for (int nt = 0; nt < 4; ++nt)
#pragma unroll
            for (int mt = 0; mt < 8; ++mt)
                acc[mt][nt] = MFMA(a[mt], b[nt], acc[mt][nt]);
#pragma unroll
        for (int mt = 0; mt < 8; ++mt) a[mt] = an[mt];
#pragma unroll
        for (int nt = 0; nt < 4; ++nt) b[nt] = bn[nt];
    }

    __syncthreads();    // all waves done reading this block's xp region
#pragma unroll
    for (int nt = 0; nt < 4; ++nt) {
        float bv = biasg[w * 64 + nt * 16 + c16];
#pragma unroll
        for (int mt = 0; mt < 8; ++mt) {
            short4v o;
#pragma unroll
            for (int r = 0; r < 4; ++r) o[r] = f2bs(acc[mt][nt][r] + bv);
            // xg tile (g, tn) at xp[g*9216 + tn*256 + lane*4]
            *(short4v*)&xp[(g0 + mt) * 9216 + (w * 4 + nt) * 256 + lane * 4] = o;
        }
    }
}

// ---------------------------------------------------------------------------
// k23: recurrence + MLP. 256 blocks x 512 thr, 64 samples/block.
// Wave w owns gate cols j in [16w,16w+16): gate tiles {g*8+w}.
// ---------------------------------------------------------------------------
__global__ __launch_bounds__(512, 2) void k23_kernel(
    const short* __restrict__ xg,      // = xp (in-place xg C-tiles)
    const short* __restrict__ Whhp, const float* __restrict__ biasg,
    const short* __restrict__ W1p, const float* __restrict__ b1p,
    const short* __restrict__ W2p, const float* __restrict__ b2,
    const short* __restrict__ W3p, const float* __restrict__ b3,
    const float* __restrict__ W4,  const float* __restrict__ b4,
    float* __restrict__ out)
{
    __shared__ __align__(16) short sA[SM_SHORTS];
    const int tid  = threadIdx.x;
    const int w    = tid >> 6;
    const int lane = tid & 63;
    const int quad = lane >> 4;
    const int c16  = lane & 15;
    const int b0   = blockIdx.x * 64;
    const int st0  = blockIdx.x * 4;        // first sample-tile
    const int j    = w * 16 + c16;

    float bg[4];
#pragma unroll
    for (int g = 0; g < 4; ++g) bg[g] = biasg[g * HH + j];

    short8 whh[4][4];
#pragma unroll
    for (int g = 0; g < 4; ++g)
#pragma unroll
        for (int ks = 0; ks < 4; ++ks)
            whh[g][ks] = *(const short8*)&Whhp[((((g * 8 + w) * 4) + ks) << 9) + lane * 8];

    float cst[4][4];
#pragma unroll
    for (int mt = 0; mt < 4; ++mt)
#pragma unroll
        for (int r = 0; r < 4; ++r) cst[mt][r] = 0.f;

    // ---------------- recurrence ----------------
    for (int t = 0; t < TT; ++t) {
        short4v xq[4][4];
#pragma unroll
        for (int mt = 0; mt < 4; ++mt) {
            int g = (st0 + mt) * TT + t;    // m-tile index
#pragma unroll
            for (int gg = 0; gg < 4; ++gg)
                xq[mt][gg] = *(const short4v*)&xg[g * 9216 + (gg * 8 + w) * 256 + lane * 4];
        }

        f32x4 acc[4][4];
#pragma unroll
        for (int mt = 0; mt < 4; ++mt)
#pragma unroll
            for (int g = 0; g < 4; ++g)
                acc[mt][g] = (f32x4){0.f, 0.f, 0.f, 0.f};

        if (t > 0) {
#pragma unroll
            for (int ks = 0; ks < 4; ++ks) {
                short8 ha[4];
#pragma unroll
                for (int mt = 0; mt < 4; ++mt)
                    ha[mt] = *(const short8*)
                        &sA[(mt * 16 + c16) * AFL_STR + (t - 1) * HH + ks * 32 + quad * 8];
#pragma unroll
                for (int mt = 0; mt < 4; ++mt)
#pragma unroll
                    for (int g = 0; g < 4; ++g)
                        acc[mt][g] = MFMA(ha[mt], whh[g][ks], acc[mt][g]);
            }
        }

#pragma unroll
        for (int mt = 0; mt < 4; ++mt) {
#pragma unroll
            for (int r = 0; r < 4; ++r) {
                int m = mt * 16 + quad * 4 + r;
                float gi = acc[mt][0][r] + b2f(xq[mt][0][r]) + bg[0];
                float gf = acc[mt][1][r] + b2f(xq[mt][1][r]) + bg[1];
                float gg = acc[mt][2][r] + b2f(xq[mt][2][r]) + bg[2];
                float go = acc[mt][3][r] + b2f(xq[mt][3][r]) + bg[3];
                float cn = sigf(gf) * cst[mt][r] + sigf(gi) * mytanh(gg);
                cst[mt][r] = cn;
                sA[m * AFL_STR + t * HH + j] = f2bs(sigf(go) * mytanh(cn));
            }
        }
        __syncthreads();
    }

    // ---------------- MLP ----------------
    // L1: K=640, N=576; 36 n-tiles, wave w gets tn = w + 8i
    {
        const int ntc = (w < 4) ? 5 : 4;
        f32x4 acc1[4][5];
#pragma unroll
        for (int mt = 0; mt < 4; ++mt)
#pragma unroll
            for (int i = 0; i < 5; ++i)
                acc1[mt][i] = (f32x4){0.f, 0.f, 0.f, 0.f};
        for (int ks = 0; ks < 20; ++ks) {
            short8 a[4];
#pragma unroll
            for (int mt = 0; mt < 4; ++mt)
                a[mt] = *(const short8*)&sA[(mt * 16 + c16) * AFL_STR + ks * 32 + quad * 8];
#pragma unroll
            for (int i = 0; i < 5; ++i) {
                if (i < ntc) {
                    int tn = w + 8 * i;
                    short8 b = *(const short8*)&W1p[((tn * 20 + ks) << 9) + lane * 8];
#pragma unroll
                    for (int mt = 0; mt < 4; ++mt)
                        acc1[mt][i] = MFMA(a[mt], b, acc1[mt][i]);
                }
            }
        }
#pragma unroll
        for (int i = 0; i < 5; ++i) {
            if (i < ntc) {
                int tn = w + 8 * i;
                int n  = tn * 16 + c16;
                float bv = b1p[n];
#pragma unroll
                for (int mt = 0; mt < 4; ++mt)
#pragma unroll
                    for (int r = 0; r < 4; ++r) {
                        int m = mt * 16 + quad * 4 + r;
                        float v = acc1[mt][i][r] + bv;
                        sA[A1_OFF + m * A1_STR + n] = f2bs(v > 0.f ? v : 0.f);
                    }
            }
        }
    }
    __syncthreads();

    // L2: K=544, N=256; wave w gets tn = 2w, 2w+1 (a2 overwrites dead aflat)
    {
        f32x4 acc2[4][2];
#pragma unroll
        for (int mt = 0; mt < 4; ++mt)
#pragma unroll
            for (int i = 0; i < 2; ++i)
                acc2[mt][i] = (f32x4){0.f, 0.f, 0.f, 0.f};
        for (int ks = 0; ks < 17; ++ks) {
            short8 a[4];
#pragma unroll
            for (int mt = 0; mt < 4; ++mt)
                a[mt] = *(const short8*)&sA[A1_OFF + (mt * 16 + c16) * A1_STR + ks * 32 + quad * 8];
#pragma unroll
            for (int i = 0; i < 2; ++i) {
                int tn = w * 2 + i;
                short8 b = *(const short8*)&W2p[((tn * 17 + ks) << 9) + lane * 8];
#pragma unroll
                for (int mt = 0; mt < 4; ++mt)
                    acc2[mt][i] = MFMA(a[mt], b, acc2[mt][i]);
            }
        }
#pragma unroll
        for (int i = 0; i < 2; ++i) {
            int n = (w * 2 + i) * 16 + c16;
            float bv = b2[n];
#pragma unroll
            for (int mt = 0; mt < 4; ++mt)
#pragma unroll
                for (int r = 0; r < 4; ++r) {
                    int m = mt * 16 + quad * 4 + r;
                    float v = acc2[mt][i][r] + bv;
                    sA[A2_OFF + m * A2_STR + n] = f2bs(v > 0.f ? v : 0.f);
                }
        }
    }
    __syncthreads();

    // L3: K=256, N=64; waves 0..3
    if (w < 4) {
        f32x4 acc3[4];
#pragma unroll
        for (int mt = 0; mt < 4; ++mt) acc3[mt] = (f32x4){0.f, 0.f, 0.f, 0.f};
#pragma unroll
        for (int ks = 0; ks < 8; ++ks) {
            short8 b = *(const short8*)&W3p[((w * 8 + ks) << 9) + lane * 8];
#pragma unroll
            for (int mt = 0; mt < 4; ++mt) {
                short8 a = *(const short8*)&sA[A2_OFF + (mt * 16 + c16) * A2_STR + ks * 32 + quad * 8];
                acc3[mt] = MFMA(a, b, acc3[mt]);
            }
        }
        int n = w * 16 + c16;
        float bv = b3[n];
#pragma unroll
        for (int mt = 0; mt < 4; ++mt)
#pragma unroll
            for (int r = 0; r < 4; ++r) {
                int m = mt * 16 + quad * 4 + r;
                float v = acc3[mt][r] + bv;
                sA[A3_OFF + m * A3_STR + n] = f2bs(v > 0.f ? v : 0.f);
            }
    }
    __syncthreads();

    // L4 + softmax: 128 threads = 64 samples x 2 classes
    if (tid < 128) {
        int m   = tid >> 1;
        int cls = tid & 1;
        float s = b4[cls];
#pragma unroll 8
        for (int k = 0; k < 64; ++k)
            s += b2f(sA[A3_OFF + m * A3_STR + k]) * W4[cls * 64 + k];
        float other = __shfl_xor(s, 1);
        float p = 1.f / (1.f + __expf(other - s));
        out[(b0 + m) * 2 + cls] = p;
    }
}

// ---------------------------------------------------------------------------
extern "C" void kernel_launch(void* const* d_in, const int* in_sizes, int n_in,
                              void* d_out, int out_size, void* d_ws, size_t ws_size,
                              hipStream_t stream)
{
    (void)in_sizes; (void)n_in; (void)out_size;
    if (ws_size < (size_t)WS_NEED) return;

    const float* x1   = (const float*)d_in[0];
    const float* x2   = (const float*)d_in[1];
    const float* W_ih = (const float*)d_in[2];
    const float* W_hh = (const float*)d_in[3];
    const float* b_ih = (const float*)d_in[4];
    const float* b_hh = (const float*)d_in[5];
    const float* W1   = (const float*)d_in[6];
    const float* b1   = (const float*)d_in[7];
    const float* W2   = (const float*)d_in[8];
    const float* b2   = (const float*)d_in[9];
    const float* W3   = (const float*)d_in[10];
    const float* b3   = (const float*)d_in[11];
    const float* W4   = (const float*)d_in[12];
    const float* b4   = (const float*)d_in[13];

    char* ws = (char*)d_ws;
    short* Wihp  = (short*)(ws + O_WIH);
    short* Whhp  = (short*)(ws + O_WHH);
    short* W1p   = (short*)(ws + O_W1);
    short* W2p   = (short*)(ws + O_W2);
    short* W3p   = (short*)(ws + O_W3);
    float* biasg = (float*)(ws + O_BG);
    float* b1p   = (float*)(ws + O_B1);
    short* xp    = (short*)(ws + O_XP);

    stage_kernel<<<NXPACK + NPREP, 256, 0, stream>>>(
        x1, x2, W_ih, W_hh, b_ih, b_hh, W1, b1, W2, W3,
        Wihp, Whhp, biasg, W1p, b1p, W2p, W3p, xp);
    k1_xgemm<<<640, 512, 0, stream>>>(xp, Wihp, biasg);
    k23_kernel<<<256, 512, 0, stream>>>(xp, Whhp, biasg,
                                        W1p, b1p, W2p, b2, W3p, b3, W4, b4,
                                        (float*)d_out);
}